// Round 1
// baseline (721.566 us; speedup 1.0000x reference)
//
#include <hip/hip_runtime.h>
#include <math.h>

#define CC 64
#define KK 20
#define DCH 32
#define LOG2E 1.4426950408889634f
#define LN2   0.6931471805599453f
#define LN2PI 1.8378770664093453f
#define BIGN  -1.0e9f

#if __has_builtin(__builtin_amdgcn_exp2f)
#define EXP2(x) __builtin_amdgcn_exp2f(x)
#else
#define EXP2(x) exp2f(x)
#endif
#if __has_builtin(__builtin_amdgcn_logf)
#define LOG2(x) __builtin_amdgcn_logf(x)
#else
#define LOG2(x) log2f(x)
#endif

template <int Ctrl, int OldBits>
__device__ __forceinline__ float dpp_mov(float x) {
  return __int_as_float(__builtin_amdgcn_update_dpp(
      OldBits, __float_as_int(x), Ctrl, 0xf, 0xf, false));
}

// ds_swizzle BitMode: offset = (xor<<10) | (or<<5) | and ; and=0x1F, or=0
template <int XOR>
__device__ __forceinline__ int swz(int x) {
  return __builtin_amdgcn_ds_swizzle(x, 0x001F | (XOR << 10));
}

__device__ __forceinline__ float wave_max64(float x) {
  constexpr int NI = (int)0xff800000;  // -inf
  x = fmaxf(x, dpp_mov<0x111, NI>(x));
  x = fmaxf(x, dpp_mov<0x112, NI>(x));
  x = fmaxf(x, dpp_mov<0x114, NI>(x));
  x = fmaxf(x, dpp_mov<0x118, NI>(x));
  x = fmaxf(x, dpp_mov<0x142, NI>(x));
  x = fmaxf(x, dpp_mov<0x143, NI>(x));
  return __int_as_float(__builtin_amdgcn_readlane(__float_as_int(x), 63));
}

__device__ __forceinline__ float wave_sum64(float x) {
  x += dpp_mov<0x111, 0>(x);
  x += dpp_mov<0x112, 0>(x);
  x += dpp_mov<0x114, 0>(x);
  x += dpp_mov<0x118, 0>(x);
  x += dpp_mov<0x142, 0>(x);
  x += dpp_mov<0x143, 0>(x);
  return __int_as_float(__builtin_amdgcn_readlane(__float_as_int(x), 63));
}

// ---------------------------------------------------------------------------
// Setup. wmat = means * sqrt(invvar) (emission folds sqrt(iv) into BOTH
// operands so the x^2 term needs no separate iv multiply). sinv = sqrt(invvar).
// ---------------------------------------------------------------------------
__global__ void setup_kernel(const float* __restrict__ means,
                             const float* __restrict__ cov,
                             const float* __restrict__ tl,
                             const float* __restrict__ il,
                             const float* __restrict__ plr,
                             float* __restrict__ wmat,
                             float* __restrict__ invvar,
                             float* __restrict__ sinv,
                             float* __restrict__ q2,
                             float* __restrict__ P_T,
                             float* __restrict__ init2,
                             float* __restrict__ len2,
                             int D) {
  __shared__ float red[256];
  int tid = threadIdx.x;
  for (int d = tid; d < D; d += 256) {
    float v = 1.0f / cov[(size_t)d * D + d];
    invvar[d] = v;
    sinv[d] = sqrtf(v);
  }
  float lp_ = 0.f;
  for (int d = tid; d < D; d += 256) lp_ += logf(cov[(size_t)d * D + d]);
  red[tid] = lp_;
  __syncthreads();
  for (int s = 128; s > 0; s >>= 1) {
    if (tid < s) red[tid] += red[tid + s];
    __syncthreads();
  }
  float logdet = red[0];
  __syncthreads();
  {
    int c = tid & 63, q = tid >> 6;
    int dq = D / 4;
    float m2p = 0.f;
    for (int d = q * dq; d < (q + 1) * dq; ++d) {
      float mu = means[c * D + d];
      m2p = fmaf(mu * mu, invvar[d], m2p);
    }
    red[tid] = m2p;
  }
  __syncthreads();
  for (int i = tid; i < CC * D; i += 256) wmat[i] = means[i] * sinv[i % D];
  if (tid < CC) {
    int c = tid;
    float m2 = red[c] + red[c + 64] + red[c + 128] + red[c + 192];
    q2[c] = -0.5f * LOG2E * (m2 + logdet + (float)D * LN2PI);
    int j = c;
    float mx = -1e30f;
    for (int i2 = 0; i2 < CC; ++i2) {
      float v = (i2 == j) ? BIGN : tl[i2 * CC + j];
      mx = fmaxf(mx, v);
    }
    float s = 0.f;
    for (int i2 = 0; i2 < CC; ++i2) {
      float v = (i2 == j) ? BIGN : tl[i2 * CC + j];
      s += expf(v - mx);
    }
    float inv = 1.f / s;
    for (int i2 = 0; i2 < CC; ++i2) {
      float v = (i2 == j) ? BIGN : tl[i2 * CC + j];
      P_T[j * CC + i2] = expf(v - mx) * inv;
    }
    float mi = -1e30f;
    for (int i2 = 0; i2 < CC; ++i2) mi = fmaxf(mi, il[i2]);
    float si = 0.f;
    for (int i2 = 0; i2 < CC; ++i2) si += expf(il[i2] - mi);
    init2[c] = LOG2E * (il[c] - (mi + logf(si)));
  }
  for (int i = tid; i < KK * CC; i += 256) {
    int k = i / CC, c = i % CC;
    float lr = plr[c];
    float lp = (float)(k + 1) * lr - expf(lr) - lgammaf((float)(k + 2));
    len2[i] = LOG2E * lp;
  }
}

// ---------------------------------------------------------------------------
// Emission v2: transposed LDS tiles (stride 68 keeps float4 alignment,
// broadcast/2-way-free reads), inner loop = 2 x ds_read_b128 + 16 fma.
// x^2 term folded out of inner loop: stage x*sqrt(iv); x2 accumulated during
// staging, quad-DPP reduced across the 4 stager threads per row.
// Next chunk's global loads prefetched into registers under compute.
// ---------------------------------------------------------------------------
__global__ __launch_bounds__(256) void emission_kernel(
    const float* __restrict__ feat,
    const float* __restrict__ wmat,
    const float* __restrict__ sinv,
    const float* __restrict__ q2,
    float* __restrict__ emhat,
    float* __restrict__ kmax,
    int D) {
  __shared__ __align__(16) float xsT[DCH][68];
  __shared__ __align__(16) float wsT[DCH][68];
  __shared__ float q2s[CC];
  __shared__ float x2row[64];
  __shared__ float rmx[64][17];
  __shared__ float kapsh[64];
  int tid = threadIdx.x;
  size_t row0 = (size_t)blockIdx.x * 64;
  if (tid < CC) q2s[tid] = q2[tid];
  int lr_ = tid >> 2;        // row (for x) / class (for w), 0..63
  int lq  = tid & 3;
  int lj  = lq * 8;          // 0,8,16,24 within chunk
  int tx = tid & 15, ty = tid >> 4;
  int r0 = ty * 4, c0 = tx * 4;

  const float* fx = feat + (row0 + (size_t)lr_) * D + lj;
  const float* fw = wmat + (size_t)lr_ * D + lj;
  const float* fs = sinv + lj;

  float4 xa = *(const float4*)(fx);
  float4 xb = *(const float4*)(fx + 4);
  float4 wa = *(const float4*)(fw);
  float4 wb = *(const float4*)(fw + 4);
  float4 sa = *(const float4*)(fs);
  float4 sb = *(const float4*)(fs + 4);

  float acc[4][4] = {{0.f}};
  float x2p = 0.f;

  for (int d0 = 0; d0 < D; d0 += DCH) {
    __syncthreads();
    {
      float xs0 = xa.x * sa.x, xs1 = xa.y * sa.y, xs2 = xa.z * sa.z, xs3 = xa.w * sa.w;
      float xs4 = xb.x * sb.x, xs5 = xb.y * sb.y, xs6 = xb.z * sb.z, xs7 = xb.w * sb.w;
      xsT[lj + 0][lr_] = xs0; xsT[lj + 1][lr_] = xs1;
      xsT[lj + 2][lr_] = xs2; xsT[lj + 3][lr_] = xs3;
      xsT[lj + 4][lr_] = xs4; xsT[lj + 5][lr_] = xs5;
      xsT[lj + 6][lr_] = xs6; xsT[lj + 7][lr_] = xs7;
      wsT[lj + 0][lr_] = wa.x; wsT[lj + 1][lr_] = wa.y;
      wsT[lj + 2][lr_] = wa.z; wsT[lj + 3][lr_] = wa.w;
      wsT[lj + 4][lr_] = wb.x; wsT[lj + 5][lr_] = wb.y;
      wsT[lj + 6][lr_] = wb.z; wsT[lj + 7][lr_] = wb.w;
      x2p = fmaf(xs0, xs0, x2p); x2p = fmaf(xs1, xs1, x2p);
      x2p = fmaf(xs2, xs2, x2p); x2p = fmaf(xs3, xs3, x2p);
      x2p = fmaf(xs4, xs4, x2p); x2p = fmaf(xs5, xs5, x2p);
      x2p = fmaf(xs6, xs6, x2p); x2p = fmaf(xs7, xs7, x2p);
    }
    __syncthreads();
    if (d0 + DCH < D) {   // prefetch next chunk under compute
      fx += DCH; fw += DCH; fs += DCH;
      xa = *(const float4*)(fx);
      xb = *(const float4*)(fx + 4);
      wa = *(const float4*)(fw);
      wb = *(const float4*)(fw + 4);
      sa = *(const float4*)(fs);
      sb = *(const float4*)(fs + 4);
    }
    #pragma unroll
    for (int j = 0; j < DCH; ++j) {
      float4 xv = *(const float4*)&xsT[j][r0];
      float4 wv = *(const float4*)&wsT[j][c0];
      acc[0][0] = fmaf(xv.x, wv.x, acc[0][0]);
      acc[0][1] = fmaf(xv.x, wv.y, acc[0][1]);
      acc[0][2] = fmaf(xv.x, wv.z, acc[0][2]);
      acc[0][3] = fmaf(xv.x, wv.w, acc[0][3]);
      acc[1][0] = fmaf(xv.y, wv.x, acc[1][0]);
      acc[1][1] = fmaf(xv.y, wv.y, acc[1][1]);
      acc[1][2] = fmaf(xv.y, wv.z, acc[1][2]);
      acc[1][3] = fmaf(xv.y, wv.w, acc[1][3]);
      acc[2][0] = fmaf(xv.z, wv.x, acc[2][0]);
      acc[2][1] = fmaf(xv.z, wv.y, acc[2][1]);
      acc[2][2] = fmaf(xv.z, wv.z, acc[2][2]);
      acc[2][3] = fmaf(xv.z, wv.w, acc[2][3]);
      acc[3][0] = fmaf(xv.w, wv.x, acc[3][0]);
      acc[3][1] = fmaf(xv.w, wv.y, acc[3][1]);
      acc[3][2] = fmaf(xv.w, wv.z, acc[3][2]);
      acc[3][3] = fmaf(xv.w, wv.w, acc[3][3]);
    }
  }

  // reduce x2 across the 4 stager threads of each row (lanes 4k..4k+3)
  x2p += dpp_mov<0xB1, 0>(x2p);   // quad_perm xor1
  x2p += dpp_mov<0x4E, 0>(x2p);   // quad_perm xor2
  if (lq == 0) x2row[lr_] = x2p;
  __syncthreads();

  float e[4][4];
  #pragma unroll
  for (int i = 0; i < 4; ++i) {
    float h = 0.5f * x2row[r0 + i];
    #pragma unroll
    for (int k2 = 0; k2 < 4; ++k2)
      e[i][k2] = LOG2E * (acc[i][k2] - h) + q2s[c0 + k2];
  }
  #pragma unroll
  for (int i = 0; i < 4; ++i)
    rmx[r0 + i][tx] = fmaxf(fmaxf(e[i][0], e[i][1]), fmaxf(e[i][2], e[i][3]));
  __syncthreads();
  if (tid < 64) {
    float m = rmx[tid][0];
    #pragma unroll
    for (int j = 1; j < 16; ++j) m = fmaxf(m, rmx[tid][j]);
    kapsh[tid] = m;
    kmax[row0 + tid] = m;
  }
  __syncthreads();
  #pragma unroll
  for (int i = 0; i < 4; ++i) {
    float kp = kapsh[r0 + i];
    size_t row = row0 + r0 + i;
    float4 o;
    o.x = EXP2(e[i][0] - kp); o.y = EXP2(e[i][1] - kp);
    o.z = EXP2(e[i][2] - kp); o.w = EXP2(e[i][3] - kp);
    *(float4*)&emhat[row * CC + c0] = o;
  }
}

// ---------------------------------------------------------------------------
// Recursion. Matvec rewritten as XOR-network broadcast:
//   vnew[c] = sum_r Q[r] * a[c^r],  Q[r]@lane c = P_T[(c^r)*CC + c]
// a[c^r] obtained by: 1 ds_bpermute (xor 32) + ds_swizzle xor{4..28} for the
// 16 base vectors, + quad_perm DPP (xor 1/2/3) for within-quad values.
// All permutes are <=2 deep from `a` and independent -> no readlane SGPR
// hazards, 15 ops moved to the DS pipe.
// ---------------------------------------------------------------------------
#define MVSTEP(k, srcv)                                                  \
  {                                                                      \
    int xr_ = ((k) % 8 == 0) ? (srcv) : swz<(4 * ((k) % 8))>(srcv);      \
    float x0_ = __int_as_float(xr_);                                     \
    float x1_ = dpp_mov<0xB1, 0>(x0_);                                   \
    float x2_ = dpp_mov<0x4E, 0>(x0_);                                   \
    float x3_ = dpp_mov<0x1B, 0>(x0_);                                   \
    m0 = fmaf(Q[4 * (k) + 0], x0_, m0);                                  \
    m1 = fmaf(Q[4 * (k) + 1], x1_, m1);                                  \
    m2 = fmaf(Q[4 * (k) + 2], x2_, m2);                                  \
    m3 = fmaf(Q[4 * (k) + 3], x3_, m3);                                  \
  }

__global__ __launch_bounds__(64, 1) void recur_kernel(
    const float* __restrict__ emhat,
    const float* __restrict__ kmax,
    const float* __restrict__ P_T,
    const float* __restrict__ init2,
    const float* __restrict__ len2,
    const int* __restrict__ lengths,
    float* __restrict__ out,
    int N) {
  int b = blockIdx.x;
  int c = threadIdx.x;
  const int bp32 = ((c ^ 32) << 2);   // ds_bpermute byte address for xor-32

  // Q[r] = P^T[c^r][c] : the coefficient that multiplies a[c^r] in lane c.
  float Q[CC];
  #pragma unroll
  for (int r = 0; r < CC; ++r) Q[r] = P_T[(size_t)(c ^ r) * CC + c];

  float W[KK + 1];
  #pragma unroll
  for (int k = 1; k <= KK; ++k) W[k] = EXP2(len2[(k - 1) * CC + c]);
  float W1 = W[1];

  const float* eh_b = emhat + (size_t)b * N * CC;
  const float* km_b = kmax + (size_t)b * N;
  int len_b = lengths[b];

  float skp = 0.f;
  for (int r = c; r < len_b; r += 64) skp += km_b[r];
  float Skap = wave_sum64(skp);

  float v = EXP2(init2[c]);
  float rho = eh_b[c];  // row 0
  float q0v = eh_b[(size_t)(1 <= N - 1 ? 1 : N - 1) * CC + c];
  float q1v = eh_b[(size_t)(2 <= N - 1 ? 2 : N - 1) * CC + c];
  float q2v = eh_b[(size_t)(3 <= N - 1 ? 3 : N - 1) * CC + c];
  float q3v = eh_b[(size_t)(4 <= N - 1 ? 4 : N - 1) * CC + c];
  float EfSum = 0.f;
  float A[KK];
  #pragma unroll
  for (int i = 0; i < KK; ++i) A[i] = 0.f;
  float rest = 0.f;

  auto body = [&](int t, float& q) {
    // ---- serial chain head ----
    float A0 = v * rho;
    float a = fmaf(A0, W1, rest);

    // issue the cross-half permute early (DS latency overlaps S2 below)
    int ai = __float_as_int(a);
    int bi = __builtin_amdgcn_ds_bpermute(bp32, ai);

    if (t == len_b) {
      float s_ = wave_sum64(a);
      if (c == 0) out[b] = LN2 * (Skap + EfSum + LOG2(s_));
    }

    // ---- S2 from OLD ring (overlaps permutes) ----
    float u0 = A0 * W[2], u1 = 0.f, u2 = 0.f, u3 = 0.f;
    #pragma unroll
    for (int i = 1; i + 3 <= 16; i += 4) {
      u0 = fmaf(A[i],     W[i + 2], u0);
      u1 = fmaf(A[i + 1], W[i + 3], u1);
      u2 = fmaf(A[i + 2], W[i + 4], u2);
      u3 = fmaf(A[i + 3], W[i + 5], u3);
    }
    u1 = fmaf(A[17], W[19], u1);
    u2 = fmaf(A[18], W[20], u2);
    float S2 = (u0 + u1) + (u2 + u3);

    // ---- matvec v_new = P . a via XOR network ----
    float m0 = 0.f, m1 = 0.f, m2 = 0.f, m3 = 0.f;
    MVSTEP(0, ai)  MVSTEP(1, ai)  MVSTEP(2, ai)  MVSTEP(3, ai)
    MVSTEP(4, ai)  MVSTEP(5, ai)  MVSTEP(6, ai)  MVSTEP(7, ai)
    MVSTEP(8, bi)  MVSTEP(9, bi)  MVSTEP(10, bi) MVSTEP(11, bi)
    MVSTEP(12, bi) MVSTEP(13, bi) MVSTEP(14, bi) MVSTEP(15, bi)
    float vnew = (m0 + m1) + (m2 + m3);

    // ---- prefetch rotation (straight-line; reload for t+4) ----
    float rh = q;
    int rown = (t + 4 <= N - 1) ? (t + 4) : (N - 1);
    q = eh_b[(size_t)rown * CC + c];

    // ---- renorm (uses OLD v; overlaps everything) ----
    float vmax = wave_max64(v);
    vmax = fminf(fmaxf(vmax, 1e-20f), 1e20f);
    int eb = (__float_as_int(vmax) >> 23) & 255;
    float scale = __int_as_float((254 - eb) << 23);
    EfSum += (float)(eb - 127);
    float rhon = rh * scale;
    rest = rhon * S2;

    // ---- ring shift (for next step's S2) ----
    #pragma unroll
    for (int i = KK - 1; i >= 2; --i) A[i] = A[i - 1] * rhon;
    A[1] = A0 * rhon;

    v = vnew;
    rho = rhon;
  };

  int t = 1;
  for (; t + 3 <= N; t += 4) {
    body(t,     q0v);
    body(t + 1, q1v);
    body(t + 2, q2v);
    body(t + 3, q3v);
  }
  for (; t <= N; ++t) {
    int s = t & 3;
    if (s == 1)      body(t, q0v);
    else if (s == 2) body(t, q1v);
    else if (s == 3) body(t, q2v);
    else             body(t, q3v);
  }
}

extern "C" void kernel_launch(void* const* d_in, const int* in_sizes, int n_in,
                              void* d_out, int out_size, void* d_ws, size_t ws_size,
                              hipStream_t stream) {
  const float* feat   = (const float*)d_in[0];
  const int*   lens   = (const int*)d_in[1];
  const float* means  = (const float*)d_in[2];
  const float* cov    = (const float*)d_in[3];
  const float* tl     = (const float*)d_in[4];
  const float* il     = (const float*)d_in[5];
  const float* plr    = (const float*)d_in[6];
  int B = in_sizes[1];
  int D = in_sizes[2] / CC;
  int N = in_sizes[0] / (B * D);

  float* ws = (float*)d_ws;
  size_t off = 0;
  float* wmat   = ws + off; off += (size_t)CC * D;
  float* invvar = ws + off; off += D;
  float* sinv   = ws + off; off += D;
  float* q2     = ws + off; off += CC;
  float* P_T    = ws + off; off += CC * CC;
  float* init2  = ws + off; off += CC;
  float* len2   = ws + off; off += KK * CC;
  float* emhat  = ws + off; off += (size_t)B * N * CC;
  float* kmax   = ws + off; off += (size_t)B * N;

  hipLaunchKernelGGL(setup_kernel, dim3(1), dim3(256), 0, stream,
                     means, cov, tl, il, plr, wmat, invvar, sinv, q2, P_T, init2, len2, D);
  hipLaunchKernelGGL(emission_kernel, dim3((B * N) / 64), dim3(256), 0, stream,
                     feat, wmat, sinv, q2, emhat, kmax, D);
  hipLaunchKernelGGL(recur_kernel, dim3(B), dim3(64), 0, stream,
                     emhat, kmax, P_T, init2, len2, lens, (float*)d_out, N);
}

// Round 3
// 609.483 us; speedup vs baseline: 1.1839x; 1.1839x over previous
//
#include <hip/hip_runtime.h>
#include <math.h>

#define CC 64
#define KK 20
#define DCH 32
#define LOG2E 1.4426950408889634f
#define LN2   0.6931471805599453f
#define LN2PI 1.8378770664093453f
#define BIGN  -1.0e9f

#if __has_builtin(__builtin_amdgcn_exp2f)
#define EXP2(x) __builtin_amdgcn_exp2f(x)
#else
#define EXP2(x) exp2f(x)
#endif
#if __has_builtin(__builtin_amdgcn_logf)
#define LOG2(x) __builtin_amdgcn_logf(x)
#else
#define LOG2(x) log2f(x)
#endif

__device__ __forceinline__ float rlane(float v, int l) {
  return __int_as_float(__builtin_amdgcn_readlane(__float_as_int(v), l));
}

template <int Ctrl, int OldBits>
__device__ __forceinline__ float dpp_mov(float x) {
  return __int_as_float(__builtin_amdgcn_update_dpp(
      OldBits, __float_as_int(x), Ctrl, 0xf, 0xf, false));
}

__device__ __forceinline__ float wave_max64(float x) {
  constexpr int NI = (int)0xff800000;  // -inf
  x = fmaxf(x, dpp_mov<0x111, NI>(x));
  x = fmaxf(x, dpp_mov<0x112, NI>(x));
  x = fmaxf(x, dpp_mov<0x114, NI>(x));
  x = fmaxf(x, dpp_mov<0x118, NI>(x));
  x = fmaxf(x, dpp_mov<0x142, NI>(x));
  x = fmaxf(x, dpp_mov<0x143, NI>(x));
  return __int_as_float(__builtin_amdgcn_readlane(__float_as_int(x), 63));
}

__device__ __forceinline__ float wave_sum64(float x) {
  x += dpp_mov<0x111, 0>(x);
  x += dpp_mov<0x112, 0>(x);
  x += dpp_mov<0x114, 0>(x);
  x += dpp_mov<0x118, 0>(x);
  x += dpp_mov<0x142, 0>(x);
  x += dpp_mov<0x143, 0>(x);
  return __int_as_float(__builtin_amdgcn_readlane(__float_as_int(x), 63));
}

// ---------------------------------------------------------------------------
// Setup (unchanged)
// ---------------------------------------------------------------------------
__global__ void setup_kernel(const float* __restrict__ means,
                             const float* __restrict__ cov,
                             const float* __restrict__ tl,
                             const float* __restrict__ il,
                             const float* __restrict__ plr,
                             float* __restrict__ wmat,
                             float* __restrict__ invvar,
                             float* __restrict__ sinv,
                             float* __restrict__ q2,
                             float* __restrict__ P_T,
                             float* __restrict__ init2,
                             float* __restrict__ len2,
                             int D) {
  __shared__ float red[256];
  int tid = threadIdx.x;
  for (int d = tid; d < D; d += 256) {
    float v = 1.0f / cov[(size_t)d * D + d];
    invvar[d] = v;
    sinv[d] = sqrtf(v);
  }
  float lp_ = 0.f;
  for (int d = tid; d < D; d += 256) lp_ += logf(cov[(size_t)d * D + d]);
  red[tid] = lp_;
  __syncthreads();
  for (int s = 128; s > 0; s >>= 1) {
    if (tid < s) red[tid] += red[tid + s];
    __syncthreads();
  }
  float logdet = red[0];
  __syncthreads();
  {
    int c = tid & 63, q = tid >> 6;
    int dq = D / 4;
    float m2p = 0.f;
    for (int d = q * dq; d < (q + 1) * dq; ++d) {
      float mu = means[c * D + d];
      m2p = fmaf(mu * mu, invvar[d], m2p);
    }
    red[tid] = m2p;
  }
  __syncthreads();
  for (int i = tid; i < CC * D; i += 256) wmat[i] = means[i] * sinv[i % D];
  if (tid < CC) {
    int c = tid;
    float m2 = red[c] + red[c + 64] + red[c + 128] + red[c + 192];
    q2[c] = -0.5f * LOG2E * (m2 + logdet + (float)D * LN2PI);
    int j = c;
    float mx = -1e30f;
    for (int i2 = 0; i2 < CC; ++i2) {
      float v = (i2 == j) ? BIGN : tl[i2 * CC + j];
      mx = fmaxf(mx, v);
    }
    float s = 0.f;
    for (int i2 = 0; i2 < CC; ++i2) {
      float v = (i2 == j) ? BIGN : tl[i2 * CC + j];
      s += expf(v - mx);
    }
    float inv = 1.f / s;
    for (int i2 = 0; i2 < CC; ++i2) {
      float v = (i2 == j) ? BIGN : tl[i2 * CC + j];
      P_T[j * CC + i2] = expf(v - mx) * inv;
    }
    float mi = -1e30f;
    for (int i2 = 0; i2 < CC; ++i2) mi = fmaxf(mi, il[i2]);
    float si = 0.f;
    for (int i2 = 0; i2 < CC; ++i2) si += expf(il[i2] - mi);
    init2[c] = LOG2E * (il[c] - (mi + logf(si)));
  }
  for (int i = tid; i < KK * CC; i += 256) {
    int k = i / CC, c = i % CC;
    float lr = plr[c];
    float lp = (float)(k + 1) * lr - expf(lr) - lgammaf((float)(k + 2));
    len2[i] = LOG2E * lp;
  }
}

// ---------------------------------------------------------------------------
// Emission (unchanged: transposed LDS tiles, folded sqrt(iv), reg prefetch)
// ---------------------------------------------------------------------------
__global__ __launch_bounds__(256) void emission_kernel(
    const float* __restrict__ feat,
    const float* __restrict__ wmat,
    const float* __restrict__ sinv,
    const float* __restrict__ q2,
    float* __restrict__ emhat,
    float* __restrict__ kmax,
    int D) {
  __shared__ __align__(16) float xsT[DCH][68];
  __shared__ __align__(16) float wsT[DCH][68];
  __shared__ float q2s[CC];
  __shared__ float x2row[64];
  __shared__ float rmx[64][17];
  __shared__ float kapsh[64];
  int tid = threadIdx.x;
  size_t row0 = (size_t)blockIdx.x * 64;
  if (tid < CC) q2s[tid] = q2[tid];
  int lr_ = tid >> 2;
  int lq  = tid & 3;
  int lj  = lq * 8;
  int tx = tid & 15, ty = tid >> 4;
  int r0 = ty * 4, c0 = tx * 4;

  const float* fx = feat + (row0 + (size_t)lr_) * D + lj;
  const float* fw = wmat + (size_t)lr_ * D + lj;
  const float* fs = sinv + lj;

  float4 xa = *(const float4*)(fx);
  float4 xb = *(const float4*)(fx + 4);
  float4 wa = *(const float4*)(fw);
  float4 wb = *(const float4*)(fw + 4);
  float4 sa = *(const float4*)(fs);
  float4 sb = *(const float4*)(fs + 4);

  float acc[4][4] = {{0.f}};
  float x2p = 0.f;

  for (int d0 = 0; d0 < D; d0 += DCH) {
    __syncthreads();
    {
      float xs0 = xa.x * sa.x, xs1 = xa.y * sa.y, xs2 = xa.z * sa.z, xs3 = xa.w * sa.w;
      float xs4 = xb.x * sb.x, xs5 = xb.y * sb.y, xs6 = xb.z * sb.z, xs7 = xb.w * sb.w;
      xsT[lj + 0][lr_] = xs0; xsT[lj + 1][lr_] = xs1;
      xsT[lj + 2][lr_] = xs2; xsT[lj + 3][lr_] = xs3;
      xsT[lj + 4][lr_] = xs4; xsT[lj + 5][lr_] = xs5;
      xsT[lj + 6][lr_] = xs6; xsT[lj + 7][lr_] = xs7;
      wsT[lj + 0][lr_] = wa.x; wsT[lj + 1][lr_] = wa.y;
      wsT[lj + 2][lr_] = wa.z; wsT[lj + 3][lr_] = wa.w;
      wsT[lj + 4][lr_] = wb.x; wsT[lj + 5][lr_] = wb.y;
      wsT[lj + 6][lr_] = wb.z; wsT[lj + 7][lr_] = wb.w;
      x2p = fmaf(xs0, xs0, x2p); x2p = fmaf(xs1, xs1, x2p);
      x2p = fmaf(xs2, xs2, x2p); x2p = fmaf(xs3, xs3, x2p);
      x2p = fmaf(xs4, xs4, x2p); x2p = fmaf(xs5, xs5, x2p);
      x2p = fmaf(xs6, xs6, x2p); x2p = fmaf(xs7, xs7, x2p);
    }
    __syncthreads();
    if (d0 + DCH < D) {
      fx += DCH; fw += DCH; fs += DCH;
      xa = *(const float4*)(fx);
      xb = *(const float4*)(fx + 4);
      wa = *(const float4*)(fw);
      wb = *(const float4*)(fw + 4);
      sa = *(const float4*)(fs);
      sb = *(const float4*)(fs + 4);
    }
    #pragma unroll
    for (int j = 0; j < DCH; ++j) {
      float4 xv = *(const float4*)&xsT[j][r0];
      float4 wv = *(const float4*)&wsT[j][c0];
      acc[0][0] = fmaf(xv.x, wv.x, acc[0][0]);
      acc[0][1] = fmaf(xv.x, wv.y, acc[0][1]);
      acc[0][2] = fmaf(xv.x, wv.z, acc[0][2]);
      acc[0][3] = fmaf(xv.x, wv.w, acc[0][3]);
      acc[1][0] = fmaf(xv.y, wv.x, acc[1][0]);
      acc[1][1] = fmaf(xv.y, wv.y, acc[1][1]);
      acc[1][2] = fmaf(xv.y, wv.z, acc[1][2]);
      acc[1][3] = fmaf(xv.y, wv.w, acc[1][3]);
      acc[2][0] = fmaf(xv.z, wv.x, acc[2][0]);
      acc[2][1] = fmaf(xv.z, wv.y, acc[2][1]);
      acc[2][2] = fmaf(xv.z, wv.z, acc[2][2]);
      acc[2][3] = fmaf(xv.z, wv.w, acc[2][3]);
      acc[3][0] = fmaf(xv.w, wv.x, acc[3][0]);
      acc[3][1] = fmaf(xv.w, wv.y, acc[3][1]);
      acc[3][2] = fmaf(xv.w, wv.z, acc[3][2]);
      acc[3][3] = fmaf(xv.w, wv.w, acc[3][3]);
    }
  }

  x2p += dpp_mov<0xB1, 0>(x2p);
  x2p += dpp_mov<0x4E, 0>(x2p);
  if (lq == 0) x2row[lr_] = x2p;
  __syncthreads();

  float e[4][4];
  #pragma unroll
  for (int i = 0; i < 4; ++i) {
    float h = 0.5f * x2row[r0 + i];
    #pragma unroll
    for (int k2 = 0; k2 < 4; ++k2)
      e[i][k2] = LOG2E * (acc[i][k2] - h) + q2s[c0 + k2];
  }
  #pragma unroll
  for (int i = 0; i < 4; ++i)
    rmx[r0 + i][tx] = fmaxf(fmaxf(e[i][0], e[i][1]), fmaxf(e[i][2], e[i][3]));
  __syncthreads();
  if (tid < 64) {
    float m = rmx[tid][0];
    #pragma unroll
    for (int j = 1; j < 16; ++j) m = fmaxf(m, rmx[tid][j]);
    kapsh[tid] = m;
    kmax[row0 + tid] = m;
  }
  __syncthreads();
  #pragma unroll
  for (int i = 0; i < 4; ++i) {
    float kp = kapsh[r0 + i];
    size_t row = row0 + r0 + i;
    float4 o;
    o.x = EXP2(e[i][0] - kp); o.y = EXP2(e[i][1] - kp);
    o.z = EXP2(e[i][2] - kp); o.w = EXP2(e[i][3] - kp);
    *(float4*)&emhat[row * CC + c0] = o;
  }
}

// ---------------------------------------------------------------------------
// Recursion v3: 4 waves per batch. Matvec split by columns — wave w handles
// j in [16w, 16w+16) with the PROVEN readlane form (16 rl + 16 fma/wave).
// Partials combined via double-buffered LDS (part[t&1][w][c]); ONE
// __syncthreads per step. All other per-lane state (ring, S2, renorm, rest)
// is replicated per wave — identical inputs => bitwise-identical replicas,
// no communication needed. Critical path/step: a -> 16rl/fma -> write ->
// barrier -> 4 reads -> 3 adds (~350cy vs ~910 single-wave).
// ---------------------------------------------------------------------------
__global__ __launch_bounds__(256, 1) void recur_kernel(
    const float* __restrict__ emhat,
    const float* __restrict__ kmax,
    const float* __restrict__ P_T,
    const float* __restrict__ init2,
    const float* __restrict__ len2,
    const int* __restrict__ lengths,
    float* __restrict__ out,
    int N) {
  __shared__ float part[2][4][64];
  int b = blockIdx.x;
  int tid = threadIdx.x;
  int c = tid & 63;
  int w = tid >> 6;          // wave id 0..3
  int wbase = w << 4;        // column block base

  // Q[jj] = P_T[(wbase+jj)*CC + c] — this wave's 16-column slice
  float Q[16];
  #pragma unroll
  for (int jj = 0; jj < 16; ++jj) Q[jj] = P_T[(size_t)(wbase + jj) * CC + c];

  float W[KK + 1];
  #pragma unroll
  for (int k = 1; k <= KK; ++k) W[k] = EXP2(len2[(k - 1) * CC + c]);
  float W1 = W[1];

  const float* eh_b = emhat + (size_t)b * N * CC;
  const float* km_b = kmax + (size_t)b * N;
  int len_b = lengths[b];

  // Skap replicated per wave (identical data => identical result)
  float skp = 0.f;
  for (int r = c; r < len_b; r += 64) skp += km_b[r];
  float Skap = wave_sum64(skp);

  float v = EXP2(init2[c]);
  float rho = eh_b[c];  // row 0
  float q0v = eh_b[(size_t)(1 <= N - 1 ? 1 : N - 1) * CC + c];
  float q1v = eh_b[(size_t)(2 <= N - 1 ? 2 : N - 1) * CC + c];
  float q2v = eh_b[(size_t)(3 <= N - 1 ? 3 : N - 1) * CC + c];
  float q3v = eh_b[(size_t)(4 <= N - 1 ? 4 : N - 1) * CC + c];
  float EfSum = 0.f;
  float A[KK];
  #pragma unroll
  for (int i = 0; i < KK; ++i) A[i] = 0.f;
  float rest = 0.f;

  auto body = [&](int t, float& q) {
    // ---- serial chain head (replicated) ----
    float A0 = v * rho;
    float a = fmaf(A0, W1, rest);

    if (t == len_b && w == 0) {
      float s_ = wave_sum64(a);
      if (c == 0) out[b] = LN2 * (Skap + EfSum + LOG2(s_));
    }

    // ---- matvec partial: this wave's 16 columns ----
    float m0 = 0.f, m1 = 0.f, m2 = 0.f, m3 = 0.f;
    #pragma unroll
    for (int jj = 0; jj < 16; jj += 4) {
      m0 = fmaf(Q[jj],     rlane(a, wbase + jj),     m0);
      m1 = fmaf(Q[jj + 1], rlane(a, wbase + jj + 1), m1);
      m2 = fmaf(Q[jj + 2], rlane(a, wbase + jj + 2), m2);
      m3 = fmaf(Q[jj + 3], rlane(a, wbase + jj + 3), m3);
    }
    part[t & 1][w][c] = (m0 + m1) + (m2 + m3);

    // ---- S2 from OLD ring (replicated; overlaps LDS round-trip) ----
    float u0 = A0 * W[2], u1 = 0.f, u2 = 0.f, u3 = 0.f;
    #pragma unroll
    for (int i = 1; i + 3 <= 16; i += 4) {
      u0 = fmaf(A[i],     W[i + 2], u0);
      u1 = fmaf(A[i + 1], W[i + 3], u1);
      u2 = fmaf(A[i + 2], W[i + 4], u2);
      u3 = fmaf(A[i + 3], W[i + 5], u3);
    }
    u1 = fmaf(A[17], W[19], u1);
    u2 = fmaf(A[18], W[20], u2);
    float S2 = (u0 + u1) + (u2 + u3);

    // ---- prefetch rotation ----
    float rh = q;
    int rown = (t + 4 <= N - 1) ? (t + 4) : (N - 1);
    q = eh_b[(size_t)rown * CC + c];

    // ---- renorm (uses OLD v; replicated) ----
    float vmax = wave_max64(v);
    vmax = fminf(fmaxf(vmax, 1e-20f), 1e20f);
    int eb = (__float_as_int(vmax) >> 23) & 255;
    float scale = __int_as_float((254 - eb) << 23);
    EfSum += (float)(eb - 127);
    float rhon = rh * scale;
    rest = rhon * S2;

    // ---- ring shift ----
    #pragma unroll
    for (int i = KK - 1; i >= 2; --i) A[i] = A[i - 1] * rhon;
    A[1] = A0 * rhon;

    // ---- combine partials (one barrier; double-buffered) ----
    __syncthreads();
    float vnew = (part[t & 1][0][c] + part[t & 1][1][c]) +
                 (part[t & 1][2][c] + part[t & 1][3][c]);

    v = vnew;
    rho = rhon;
  };

  int t = 1;
  for (; t + 3 <= N; t += 4) {
    body(t,     q0v);
    body(t + 1, q1v);
    body(t + 2, q2v);
    body(t + 3, q3v);
  }
  for (; t <= N; ++t) {
    int s = t & 3;
    if (s == 1)      body(t, q0v);
    else if (s == 2) body(t, q1v);
    else if (s == 3) body(t, q2v);
    else             body(t, q3v);
  }
}

extern "C" void kernel_launch(void* const* d_in, const int* in_sizes, int n_in,
                              void* d_out, int out_size, void* d_ws, size_t ws_size,
                              hipStream_t stream) {
  const float* feat   = (const float*)d_in[0];
  const int*   lens   = (const int*)d_in[1];
  const float* means  = (const float*)d_in[2];
  const float* cov    = (const float*)d_in[3];
  const float* tl     = (const float*)d_in[4];
  const float* il     = (const float*)d_in[5];
  const float* plr    = (const float*)d_in[6];
  int B = in_sizes[1];
  int D = in_sizes[2] / CC;
  int N = in_sizes[0] / (B * D);

  float* ws = (float*)d_ws;
  size_t off = 0;
  float* wmat   = ws + off; off += (size_t)CC * D;
  float* invvar = ws + off; off += D;
  float* sinv   = ws + off; off += D;
  float* q2     = ws + off; off += CC;
  float* P_T    = ws + off; off += CC * CC;
  float* init2  = ws + off; off += CC;
  float* len2   = ws + off; off += KK * CC;
  float* emhat  = ws + off; off += (size_t)B * N * CC;
  float* kmax   = ws + off; off += (size_t)B * N;

  hipLaunchKernelGGL(setup_kernel, dim3(1), dim3(256), 0, stream,
                     means, cov, tl, il, plr, wmat, invvar, sinv, q2, P_T, init2, len2, D);
  hipLaunchKernelGGL(emission_kernel, dim3((B * N) / 64), dim3(256), 0, stream,
                     feat, wmat, sinv, q2, emhat, kmax, D);
  hipLaunchKernelGGL(recur_kernel, dim3(B), dim3(256), 0, stream,
                     emhat, kmax, P_T, init2, len2, lens, (float*)d_out, N);
}